// Round 1
// baseline (443.060 us; speedup 1.0000x reference)
//
#include <hip/hip_runtime.h>

#define N_NODES 50000
#define N_EDGES 600000
#define HDIM 128
#define EPS 1e-5f
#define KC 64
#define TM 64

// ---------------- edge_index dtype detection (int32 vs int64) ----------------
// If the buffer is int64 (little-endian), words at odd int32 positions are the
// high words of src[0..1023] -> all zero (values < 50000). For int32 layout
// those positions are random src values -> essentially never all zero.
__global__ void detect_kernel(const int* __restrict__ ei, int* __restrict__ flag) {
    __shared__ int nonzero;
    if (threadIdx.x == 0) nonzero = 0;
    __syncthreads();
    int acc = 0;
    for (int i = threadIdx.x; i < 1024; i += blockDim.x)
        acc |= ei[2 * i + 1];
    if (acc) atomicOr(&nonzero, 1);
    __syncthreads();
    if (threadIdx.x == 0) *flag = (nonzero == 0) ? 1 : 0;
}

__device__ __forceinline__ int load_idx(const int* __restrict__ ei, int pos, int f) {
    return f ? ei[2 * pos] : ei[pos];
}

// ---------------- degree / CSR build ----------------
__global__ void deg_kernel(const int* __restrict__ ei, const int* __restrict__ flag,
                           int* __restrict__ deg) {
    int e = blockIdx.x * blockDim.x + threadIdx.x;
    if (e >= N_EDGES) return;
    int f = *flag;
    int d = load_idx(ei, N_EDGES + e, f);
    atomicAdd(&deg[d], 1);
}

__global__ void dinv_kernel(const int* __restrict__ deg, float* __restrict__ dinv) {
    int i = blockIdx.x * blockDim.x + threadIdx.x;
    if (i < N_NODES) dinv[i] = rsqrtf((float)deg[i] + 1.0f); // +1 self-loop
}

__global__ void block_sum(const int* __restrict__ deg, int* __restrict__ bsum) {
    __shared__ int sm[256];
    int i = blockIdx.x * 256 + threadIdx.x;
    sm[threadIdx.x] = (i < N_NODES) ? deg[i] : 0;
    __syncthreads();
    for (int s = 128; s > 0; s >>= 1) {
        if (threadIdx.x < s) sm[threadIdx.x] += sm[threadIdx.x + s];
        __syncthreads();
    }
    if (threadIdx.x == 0) bsum[blockIdx.x] = sm[0];
}

__global__ void scan_bsums(const int* __restrict__ bsum, int* __restrict__ boff, int nb) {
    __shared__ int sm[256];
    int t = threadIdx.x;
    int v = (t < nb) ? bsum[t] : 0;
    sm[t] = v;
    __syncthreads();
    for (int s = 1; s < 256; s <<= 1) {
        int add = (t >= s) ? sm[t - s] : 0;
        __syncthreads();
        sm[t] += add;
        __syncthreads();
    }
    if (t < nb) boff[t] = sm[t] - v; // exclusive
}

__global__ void scan_block(const int* __restrict__ deg, const int* __restrict__ boff,
                           int* __restrict__ rowst) {
    __shared__ int sm[256];
    int t = threadIdx.x;
    int i = blockIdx.x * 256 + t;
    int v = (i < N_NODES) ? deg[i] : 0;
    sm[t] = v;
    __syncthreads();
    for (int s = 1; s < 256; s <<= 1) {
        int add = (t >= s) ? sm[t - s] : 0;
        __syncthreads();
        sm[t] += add;
        __syncthreads();
    }
    int excl = boff[blockIdx.x] + sm[t] - v;
    if (i < N_NODES) rowst[i] = excl;
    if (i == N_NODES - 1) rowst[N_NODES] = excl + v;
}

__global__ void scatter_kernel(const int* __restrict__ ei, const int* __restrict__ flag,
                               const int* __restrict__ rowst, int* __restrict__ fill,
                               int* __restrict__ csr) {
    int e = blockIdx.x * blockDim.x + threadIdx.x;
    if (e >= N_EDGES) return;
    int f = *flag;
    int s = load_idx(ei, e, f);
    int d = load_idx(ei, N_EDGES + e, f);
    int pos = rowst[d] + atomicAdd(&fill[d], 1);
    csr[pos] = s;
}

// ---------------- aggregation: hagg[d] = dinv[d]*(sum_{s in in(d)} dinv[s]*h[s] + dinv[d]*h[d]) ----------------
__global__ __launch_bounds__(256) void agg_kernel(const float* __restrict__ h,
                                                  const float* __restrict__ dinv,
                                                  const int* __restrict__ rowst,
                                                  const int* __restrict__ csr,
                                                  float* __restrict__ out) {
    int node = blockIdx.x * 4 + (threadIdx.x >> 6);
    int lane = threadIdx.x & 63;
    if (node >= N_NODES) return;
    const float2* h2 = (const float2*)h;
    float dd = dinv[node];
    float2 v = h2[(size_t)node * 64 + lane];
    float ax = dd * v.x, ay = dd * v.y; // self-loop term (gets *dd again below)
    int e0 = rowst[node], e1 = rowst[node + 1];
    for (int e = e0; e < e1; ++e) {
        int s = csr[e];
        float w = dinv[s];
        float2 u = h2[(size_t)s * 64 + lane];
        ax += w * u.x;
        ay += w * u.y;
    }
    float2 r;
    r.x = ax * dd;
    r.y = ay * dd;
    ((float2*)out)[(size_t)node * 64 + lane] = r;
}

// ---------------- fused GEMM: out = epilogue(A @ W + bias) ----------------
// mode 0: LayerNorm(.)*gamma+beta then ReLU     mode 1: ReLU only
__global__ __launch_bounds__(256) void gemm_fused(const float* __restrict__ A,
                                                  const float* __restrict__ W,
                                                  const float* __restrict__ bias,
                                                  const float* __restrict__ gamma,
                                                  const float* __restrict__ beta,
                                                  float* __restrict__ out,
                                                  int mode, int nrows) {
    __shared__ float Wl[KC][HDIM];     // 32 KB
    __shared__ float Al[TM][KC + 4];   // 17 KB, padded stride 68
    int t = threadIdx.x;
    int rowg = t >> 4;   // 0..15
    int colg = t & 15;   // 0..15
    int r0 = rowg * 4;
    int c0 = colg * 8;
    int blockRow = blockIdx.x * TM;

    float acc[4][8];
#pragma unroll
    for (int i = 0; i < 4; ++i)
#pragma unroll
        for (int j = 0; j < 8; ++j) acc[i][j] = 0.f;

    for (int kc = 0; kc < HDIM; kc += KC) {
        // stage W chunk [KC][128]
#pragma unroll
        for (int i = 0; i < 8; ++i) {
            int idx = t + i * 256;         // 2048 float4
            int kk = idx >> 5;             // 32 float4 per row
            int cc = (idx & 31) << 2;
            *(float4*)&Wl[kk][cc] = *(const float4*)&W[(size_t)(kc + kk) * HDIM + cc];
        }
        // stage A chunk [TM][KC]
#pragma unroll
        for (int i = 0; i < 4; ++i) {
            int idx = t + i * 256;         // 1024 float4
            int rr = idx >> 4;             // 16 float4 per row
            int kk = (idx & 15) << 2;
            int grow = blockRow + rr;
            float4 v = make_float4(0.f, 0.f, 0.f, 0.f);
            if (grow < nrows) v = *(const float4*)&A[(size_t)grow * HDIM + kc + kk];
            *(float4*)&Al[rr][kk] = v;
        }
        __syncthreads();
#pragma unroll 8
        for (int kk = 0; kk < KC; ++kk) {
            float av[4];
            av[0] = Al[r0 + 0][kk];
            av[1] = Al[r0 + 1][kk];
            av[2] = Al[r0 + 2][kk];
            av[3] = Al[r0 + 3][kk];
            float4 w0 = *(const float4*)&Wl[kk][c0];
            float4 w1 = *(const float4*)&Wl[kk][c0 + 4];
            float wv[8] = {w0.x, w0.y, w0.z, w0.w, w1.x, w1.y, w1.z, w1.w};
#pragma unroll
            for (int ii = 0; ii < 4; ++ii)
#pragma unroll
                for (int jj = 0; jj < 8; ++jj) acc[ii][jj] += av[ii] * wv[jj];
        }
        __syncthreads();
    }

    int baseRow = blockRow + r0;
    if (mode == 0) {
#pragma unroll
        for (int i = 0; i < 4; ++i) {
            float v[8];
            float s1 = 0.f, s2 = 0.f;
#pragma unroll
            for (int j = 0; j < 8; ++j) {
                v[j] = acc[i][j] + bias[c0 + j];
                s1 += v[j];
                s2 += v[j] * v[j];
            }
#pragma unroll
            for (int m = 1; m <= 8; m <<= 1) {
                s1 += __shfl_xor(s1, m);
                s2 += __shfl_xor(s2, m);
            }
            float mean = s1 * (1.0f / 128.0f);
            float var = s2 * (1.0f / 128.0f) - mean * mean;
            float rs = rsqrtf(var + EPS);
            int row = baseRow + i;
            if (row < nrows) {
                float o[8];
#pragma unroll
                for (int j = 0; j < 8; ++j) {
                    float y = (v[j] - mean) * rs * gamma[c0 + j] + beta[c0 + j];
                    o[j] = y > 0.f ? y : 0.f;
                }
                *(float4*)&out[(size_t)row * HDIM + c0] = make_float4(o[0], o[1], o[2], o[3]);
                *(float4*)&out[(size_t)row * HDIM + c0 + 4] = make_float4(o[4], o[5], o[6], o[7]);
            }
        }
    } else {
#pragma unroll
        for (int i = 0; i < 4; ++i) {
            int row = baseRow + i;
            if (row < nrows) {
                float o[8];
#pragma unroll
                for (int j = 0; j < 8; ++j) {
                    float y = acc[i][j] + bias[c0 + j];
                    o[j] = y > 0.f ? y : 0.f;
                }
                *(float4*)&out[(size_t)row * HDIM + c0] = make_float4(o[0], o[1], o[2], o[3]);
                *(float4*)&out[(size_t)row * HDIM + c0 + 4] = make_float4(o[4], o[5], o[6], o[7]);
            }
        }
    }
}

// ---------------- head: logits[n] = dot(h[n], w2) + b2 ----------------
__global__ __launch_bounds__(256) void head_dot(const float* __restrict__ h,
                                                const float* __restrict__ w2,
                                                const float* __restrict__ b2,
                                                float* __restrict__ out) {
    int node = blockIdx.x * 4 + (threadIdx.x >> 6);
    int lane = threadIdx.x & 63;
    if (node >= N_NODES) return;
    float2 hv = ((const float2*)h)[(size_t)node * 64 + lane];
    float2 wv = ((const float2*)w2)[lane];
    float s = hv.x * wv.x + hv.y * wv.y;
#pragma unroll
    for (int m = 32; m > 0; m >>= 1) s += __shfl_xor(s, m);
    if (lane == 0) out[node] = s + b2[0];
}

extern "C" void kernel_launch(void* const* d_in, const int* in_sizes, int n_in,
                              void* d_out, int out_size, void* d_ws, size_t ws_size,
                              hipStream_t stream) {
    (void)in_sizes; (void)n_in; (void)out_size; (void)ws_size;
    const float* x   = (const float*)d_in[0];
    const int*   ei  = (const int*)d_in[1];
    const float* W0  = (const float*)d_in[2];
    const float* b0  = (const float*)d_in[3];
    const float* g0  = (const float*)d_in[4];
    const float* be0 = (const float*)d_in[5];
    const float* W1  = (const float*)d_in[6];
    const float* b1  = (const float*)d_in[7];
    const float* g1  = (const float*)d_in[8];
    const float* be1 = (const float*)d_in[9];
    const float* W2  = (const float*)d_in[10];
    const float* b2  = (const float*)d_in[11];
    const float* g2  = (const float*)d_in[12];
    const float* be2 = (const float*)d_in[13];
    const float* hW1 = (const float*)d_in[14];
    const float* hb1 = (const float*)d_in[15];
    const float* hW2 = (const float*)d_in[16];
    const float* hb2 = (const float*)d_in[17];
    float* out = (float*)d_out;

    char* w = (char*)d_ws;
    size_t off = 0;
    auto alloc = [&](size_t bytes) -> void* {
        void* p = w + off;
        off += (bytes + 255) & ~(size_t)255;
        return p;
    };
    float* dinv  = (float*)alloc((size_t)N_NODES * 4);
    int*   deg   = (int*)alloc((size_t)N_NODES * 4);
    int*   fill  = (int*)alloc((size_t)N_NODES * 4);
    int*   rowst = (int*)alloc((size_t)(N_NODES + 1) * 4);
    int*   csr   = (int*)alloc((size_t)N_EDGES * 4);
    int*   bsum  = (int*)alloc(256 * 4);
    int*   boff  = (int*)alloc(256 * 4);
    int*   flag  = (int*)alloc(256);
    float* hagg  = (float*)alloc((size_t)N_NODES * HDIM * 4);
    float* hbuf  = (float*)alloc((size_t)N_NODES * HDIM * 4);

    hipMemsetAsync(deg, 0, (size_t)N_NODES * 4, stream);
    hipMemsetAsync(fill, 0, (size_t)N_NODES * 4, stream);

    detect_kernel<<<1, 256, 0, stream>>>(ei, flag);
    deg_kernel<<<(N_EDGES + 255) / 256, 256, 0, stream>>>(ei, flag, deg);
    dinv_kernel<<<(N_NODES + 255) / 256, 256, 0, stream>>>(deg, dinv);
    int nb = (N_NODES + 255) / 256; // 196
    block_sum<<<nb, 256, 0, stream>>>(deg, bsum);
    scan_bsums<<<1, 256, 0, stream>>>(bsum, boff, nb);
    scan_block<<<nb, 256, 0, stream>>>(deg, boff, rowst);
    scatter_kernel<<<(N_EDGES + 255) / 256, 256, 0, stream>>>(ei, flag, rowst, fill, csr);

    const float* Ws[3]  = {W0, W1, W2};
    const float* bs[3]  = {b0, b1, b2};
    const float* gs[3]  = {g0, g1, g2};
    const float* bes[3] = {be0, be1, be2};
    const float* hin = x;
    for (int l = 0; l < 3; ++l) {
        agg_kernel<<<(N_NODES + 3) / 4, 256, 0, stream>>>(hin, dinv, rowst, csr, hagg);
        gemm_fused<<<(N_NODES + TM - 1) / TM, 256, 0, stream>>>(hagg, Ws[l], bs[l], gs[l], bes[l],
                                                                hbuf, 0, N_NODES);
        hin = hbuf;
    }
    // head layer 1: ReLU(h @ hW1 + hb1) -> hagg (reuse)
    gemm_fused<<<(N_NODES + TM - 1) / TM, 256, 0, stream>>>(hbuf, hW1, hb1, nullptr, nullptr,
                                                            hagg, 1, N_NODES);
    // head layer 2: dot with hW2
    head_dot<<<(N_NODES + 3) / 4, 256, 0, stream>>>(hagg, hW2, hb2, out);
}

// Round 2
// 304.376 us; speedup vs baseline: 1.4556x; 1.4556x over previous
//
#include <hip/hip_runtime.h>

#define N_NODES 50000
#define N_EDGES 600000
#define HDIM 128
#define EPS 1e-5f

typedef __attribute__((ext_vector_type(8))) short bf16x8;
typedef __attribute__((ext_vector_type(4))) float f32x4;

// ---------------- edge_index dtype detection (int32 vs int64) ----------------
__global__ void detect_kernel(const int* __restrict__ ei, int* __restrict__ flag) {
    __shared__ int nonzero;
    if (threadIdx.x == 0) nonzero = 0;
    __syncthreads();
    int acc = 0;
    for (int i = threadIdx.x; i < 1024; i += blockDim.x)
        acc |= ei[2 * i + 1];
    if (acc) atomicOr(&nonzero, 1);
    __syncthreads();
    if (threadIdx.x == 0) *flag = (nonzero == 0) ? 1 : 0;
}

__device__ __forceinline__ int load_idx(const int* __restrict__ ei, int pos, int f) {
    return f ? ei[2 * pos] : ei[pos];
}

// ---------------- degree / CSR build ----------------
__global__ void deg_kernel(const int* __restrict__ ei, const int* __restrict__ flag,
                           int* __restrict__ deg) {
    int e = blockIdx.x * blockDim.x + threadIdx.x;
    if (e >= N_EDGES) return;
    int f = *flag;
    int d = load_idx(ei, N_EDGES + e, f);
    atomicAdd(&deg[d], 1);
}

__global__ void dinv_kernel(const int* __restrict__ deg, float* __restrict__ dinv) {
    int i = blockIdx.x * blockDim.x + threadIdx.x;
    if (i < N_NODES) dinv[i] = rsqrtf((float)deg[i] + 1.0f); // +1 self-loop
}

__global__ void block_sum(const int* __restrict__ deg, int* __restrict__ bsum) {
    __shared__ int sm[256];
    int i = blockIdx.x * 256 + threadIdx.x;
    sm[threadIdx.x] = (i < N_NODES) ? deg[i] : 0;
    __syncthreads();
    for (int s = 128; s > 0; s >>= 1) {
        if (threadIdx.x < s) sm[threadIdx.x] += sm[threadIdx.x + s];
        __syncthreads();
    }
    if (threadIdx.x == 0) bsum[blockIdx.x] = sm[0];
}

__global__ void scan_bsums(const int* __restrict__ bsum, int* __restrict__ boff, int nb) {
    __shared__ int sm[256];
    int t = threadIdx.x;
    int v = (t < nb) ? bsum[t] : 0;
    sm[t] = v;
    __syncthreads();
    for (int s = 1; s < 256; s <<= 1) {
        int add = (t >= s) ? sm[t - s] : 0;
        __syncthreads();
        sm[t] += add;
        __syncthreads();
    }
    if (t < nb) boff[t] = sm[t] - v; // exclusive
}

__global__ void scan_block(const int* __restrict__ deg, const int* __restrict__ boff,
                           int* __restrict__ rowst) {
    __shared__ int sm[256];
    int t = threadIdx.x;
    int i = blockIdx.x * 256 + t;
    int v = (i < N_NODES) ? deg[i] : 0;
    sm[t] = v;
    __syncthreads();
    for (int s = 1; s < 256; s <<= 1) {
        int add = (t >= s) ? sm[t - s] : 0;
        __syncthreads();
        sm[t] += add;
        __syncthreads();
    }
    int excl = boff[blockIdx.x] + sm[t] - v;
    if (i < N_NODES) rowst[i] = excl;
    if (i == N_NODES - 1) rowst[N_NODES] = excl + v;
}

// scatter also precomputes per-edge weight cw = dinv[src] (kills dependent gather in agg)
__global__ void scatter_kernel(const int* __restrict__ ei, const int* __restrict__ flag,
                               const int* __restrict__ rowst, const float* __restrict__ dinv,
                               int* __restrict__ fill, int* __restrict__ csr,
                               float* __restrict__ cw) {
    int e = blockIdx.x * blockDim.x + threadIdx.x;
    if (e >= N_EDGES) return;
    int f = *flag;
    int s = load_idx(ei, e, f);
    int d = load_idx(ei, N_EDGES + e, f);
    int pos = rowst[d] + atomicAdd(&fill[d], 1);
    csr[pos] = s;
    cw[pos] = dinv[s];
}

// ---------------- aggregation (4x unrolled for MLP) ----------------
__global__ __launch_bounds__(256) void agg_kernel(const float* __restrict__ h,
                                                  const float* __restrict__ dinv,
                                                  const int* __restrict__ rowst,
                                                  const int* __restrict__ csr,
                                                  const float* __restrict__ cw,
                                                  float* __restrict__ out) {
    int node = blockIdx.x * 4 + (threadIdx.x >> 6);
    int lane = threadIdx.x & 63;
    if (node >= N_NODES) return;
    const float2* h2 = (const float2*)h;
    float dd = dinv[node];
    float2 v = h2[(size_t)node * 64 + lane];
    float ax = dd * v.x, ay = dd * v.y; // self-loop (gets *dd below)
    int e = rowst[node], e1 = rowst[node + 1];
    for (; e + 4 <= e1; e += 4) {
        int s0 = csr[e], s1 = csr[e + 1], s2 = csr[e + 2], s3 = csr[e + 3];
        float w0 = cw[e], w1 = cw[e + 1], w2 = cw[e + 2], w3 = cw[e + 3];
        float2 u0 = h2[(size_t)s0 * 64 + lane];
        float2 u1 = h2[(size_t)s1 * 64 + lane];
        float2 u2 = h2[(size_t)s2 * 64 + lane];
        float2 u3 = h2[(size_t)s3 * 64 + lane];
        ax += w0 * u0.x; ay += w0 * u0.y;
        ax += w1 * u1.x; ay += w1 * u1.y;
        ax += w2 * u2.x; ay += w2 * u2.y;
        ax += w3 * u3.x; ay += w3 * u3.y;
    }
    for (; e < e1; ++e) {
        int s = csr[e];
        float w = cw[e];
        float2 u = h2[(size_t)s * 64 + lane];
        ax += w * u.x; ay += w * u.y;
    }
    float2 r;
    r.x = ax * dd;
    r.y = ay * dd;
    ((float2*)out)[(size_t)node * 64 + lane] = r;
}

// ---------------- bf16 hi/lo split ----------------
__device__ __forceinline__ void bsplit(float a, short& hi, short& lo) {
    unsigned u = __float_as_uint(a);
    unsigned r = (u + 0x7FFFu + ((u >> 16) & 1u)) & 0xFFFF0000u; // RNE
    hi = (short)(r >> 16);
    float l = a - __uint_as_float(r);
    unsigned ul = __float_as_uint(l);
    unsigned rl = ul + 0x7FFFu + ((ul >> 16) & 1u);
    lo = (short)(rl >> 16);
}

// ---------------- pack W [128][128] fp32 -> per-lane MFMA B-fragments (hi/lo bf16) ----------------
// layout: frag index = ((ks*8 + cf)*64 + lane), 8 contiguous bf16 each.
// lane holds B[k = ks*32 + (lane>>4)*8 + i][col = cf*16 + (lane&15)]
__global__ void pack_w(const float* __restrict__ W0, const float* __restrict__ W1,
                       const float* __restrict__ W2, const float* __restrict__ W3,
                       short* __restrict__ pkh, short* __restrict__ pkl) {
    const float* W = (blockIdx.y == 0) ? W0 : (blockIdx.y == 1) ? W1
                   : (blockIdx.y == 2) ? W2 : W3;
    int idx = blockIdx.x * 256 + threadIdx.x; // 0..2047
    int lane = idx & 63;
    int cf = (idx >> 6) & 7;
    int ks = idx >> 9;
    int col = cf * 16 + (lane & 15);
    int k0 = ks * 32 + (lane >> 4) * 8;
    short h[8], l[8];
#pragma unroll
    for (int i = 0; i < 8; ++i) bsplit(W[(size_t)(k0 + i) * HDIM + col], h[i], l[i]);
    size_t base = (size_t)blockIdx.y * 16384 + (size_t)idx * 8;
#pragma unroll
    for (int i = 0; i < 8; ++i) { pkh[base + i] = h[i]; pkl[base + i] = l[i]; }
}

// ---------------- MFMA GEMM: out = epilogue(A @ W + bias), bf16x3 split ----------------
// 256 thr = 4 waves; wave handles 16 rows x 128 cols; block = 64 rows.
// mode 0: LN*gamma+beta then ReLU; mode 1: ReLU only.
__global__ __launch_bounds__(256) void gemm_mfma(const float* __restrict__ A,
                                                 const short* __restrict__ Bh,
                                                 const short* __restrict__ Bl,
                                                 const float* __restrict__ bias,
                                                 const float* __restrict__ gamma,
                                                 const float* __restrict__ beta,
                                                 float* __restrict__ out,
                                                 int mode, int nrows) {
    int t = threadIdx.x;
    int wave = t >> 6, lane = t & 63;
    int lrow = lane & 15, lk = lane >> 4;
    int rowb = blockIdx.x * 64 + wave * 16;

    f32x4 acc[8];
#pragma unroll
    for (int cf = 0; cf < 8; ++cf) acc[cf] = (f32x4){0.f, 0.f, 0.f, 0.f};

    const float* arow = A + (size_t)(rowb + lrow) * HDIM;

#pragma unroll
    for (int ks = 0; ks < 4; ++ks) {
        const float* ap = arow + ks * 32 + lk * 8;
        float4 a0 = *(const float4*)ap;
        float4 a1 = *(const float4*)(ap + 4);
        float av[8] = {a0.x, a0.y, a0.z, a0.w, a1.x, a1.y, a1.z, a1.w};
        bf16x8 ah, al;
#pragma unroll
        for (int i = 0; i < 8; ++i) {
            short hh, ll;
            bsplit(av[i], hh, ll);
            ah[i] = hh; al[i] = ll;
        }
        const short* bhp = Bh + (size_t)(ks * 8) * 64 * 8 + (size_t)lane * 8;
        const short* blp = Bl + (size_t)(ks * 8) * 64 * 8 + (size_t)lane * 8;
#pragma unroll
        for (int cf = 0; cf < 8; ++cf) {
            bf16x8 bh = *(const bf16x8*)(bhp + (size_t)cf * 512);
            bf16x8 bl = *(const bf16x8*)(blp + (size_t)cf * 512);
            acc[cf] = __builtin_amdgcn_mfma_f32_16x16x32_bf16(ah, bh, acc[cf], 0, 0, 0);
            acc[cf] = __builtin_amdgcn_mfma_f32_16x16x32_bf16(ah, bl, acc[cf], 0, 0, 0);
            acc[cf] = __builtin_amdgcn_mfma_f32_16x16x32_bf16(al, bh, acc[cf], 0, 0, 0);
        }
    }

    // epilogue: C/D layout col = cf*16 + lrow, local row = lk*4 + r
    float bias_v[8];
#pragma unroll
    for (int cf = 0; cf < 8; ++cf) bias_v[cf] = bias[cf * 16 + lrow];

    if (mode == 0) {
        float gam[8], bet[8];
#pragma unroll
        for (int cf = 0; cf < 8; ++cf) {
            gam[cf] = gamma[cf * 16 + lrow];
            bet[cf] = beta[cf * 16 + lrow];
        }
#pragma unroll
        for (int r = 0; r < 4; ++r) {
            float vv[8];
            float s1 = 0.f, s2 = 0.f;
#pragma unroll
            for (int cf = 0; cf < 8; ++cf) {
                vv[cf] = acc[cf][r] + bias_v[cf];
                s1 += vv[cf];
                s2 += vv[cf] * vv[cf];
            }
#pragma unroll
            for (int m = 1; m <= 8; m <<= 1) {
                s1 += __shfl_xor(s1, m);
                s2 += __shfl_xor(s2, m);
            }
            float mean = s1 * (1.0f / 128.0f);
            float var = s2 * (1.0f / 128.0f) - mean * mean;
            float rs = rsqrtf(var + EPS);
            int row = rowb + lk * 4 + r;
            if (row < nrows) {
#pragma unroll
                for (int cf = 0; cf < 8; ++cf) {
                    float y = (vv[cf] - mean) * rs * gam[cf] + bet[cf];
                    out[(size_t)row * HDIM + cf * 16 + lrow] = y > 0.f ? y : 0.f;
                }
            }
        }
    } else {
#pragma unroll
        for (int r = 0; r < 4; ++r) {
            int row = rowb + lk * 4 + r;
            if (row < nrows) {
#pragma unroll
                for (int cf = 0; cf < 8; ++cf) {
                    float y = acc[cf][r] + bias_v[cf];
                    out[(size_t)row * HDIM + cf * 16 + lrow] = y > 0.f ? y : 0.f;
                }
            }
        }
    }
}

// ---------------- head: logits[n] = dot(h[n], w2) + b2 ----------------
__global__ __launch_bounds__(256) void head_dot(const float* __restrict__ h,
                                                const float* __restrict__ w2,
                                                const float* __restrict__ b2,
                                                float* __restrict__ out) {
    int node = blockIdx.x * 4 + (threadIdx.x >> 6);
    int lane = threadIdx.x & 63;
    if (node >= N_NODES) return;
    float2 hv = ((const float2*)h)[(size_t)node * 64 + lane];
    float2 wv = ((const float2*)w2)[lane];
    float s = hv.x * wv.x + hv.y * wv.y;
#pragma unroll
    for (int m = 32; m > 0; m >>= 1) s += __shfl_xor(s, m);
    if (lane == 0) out[node] = s + b2[0];
}

extern "C" void kernel_launch(void* const* d_in, const int* in_sizes, int n_in,
                              void* d_out, int out_size, void* d_ws, size_t ws_size,
                              hipStream_t stream) {
    (void)in_sizes; (void)n_in; (void)out_size; (void)ws_size;
    const float* x   = (const float*)d_in[0];
    const int*   ei  = (const int*)d_in[1];
    const float* W0  = (const float*)d_in[2];
    const float* b0  = (const float*)d_in[3];
    const float* g0  = (const float*)d_in[4];
    const float* be0 = (const float*)d_in[5];
    const float* W1  = (const float*)d_in[6];
    const float* b1  = (const float*)d_in[7];
    const float* g1  = (const float*)d_in[8];
    const float* be1 = (const float*)d_in[9];
    const float* W2  = (const float*)d_in[10];
    const float* b2  = (const float*)d_in[11];
    const float* g2  = (const float*)d_in[12];
    const float* be2 = (const float*)d_in[13];
    const float* hW1 = (const float*)d_in[14];
    const float* hb1 = (const float*)d_in[15];
    const float* hW2 = (const float*)d_in[16];
    const float* hb2 = (const float*)d_in[17];
    float* out = (float*)d_out;

    char* w = (char*)d_ws;
    size_t off = 0;
    auto alloc = [&](size_t bytes) -> void* {
        void* p = w + off;
        off += (bytes + 255) & ~(size_t)255;
        return p;
    };
    float* dinv  = (float*)alloc((size_t)N_NODES * 4);
    int*   deg   = (int*)alloc((size_t)N_NODES * 4);
    int*   fill  = (int*)alloc((size_t)N_NODES * 4);
    int*   rowst = (int*)alloc((size_t)(N_NODES + 1) * 4);
    int*   csr   = (int*)alloc((size_t)N_EDGES * 4);
    float* cw    = (float*)alloc((size_t)N_EDGES * 4);
    int*   bsum  = (int*)alloc(256 * 4);
    int*   boff  = (int*)alloc(256 * 4);
    int*   flag  = (int*)alloc(256);
    float* hagg  = (float*)alloc((size_t)N_NODES * HDIM * 4);
    float* hbuf  = (float*)alloc((size_t)N_NODES * HDIM * 4);
    short* pkh   = (short*)alloc((size_t)4 * 16384 * 2); // 4 weights x 16384 bf16
    short* pkl   = (short*)alloc((size_t)4 * 16384 * 2);

    hipMemsetAsync(deg, 0, (size_t)N_NODES * 4, stream);
    hipMemsetAsync(fill, 0, (size_t)N_NODES * 4, stream);

    detect_kernel<<<1, 256, 0, stream>>>(ei, flag);
    deg_kernel<<<(N_EDGES + 255) / 256, 256, 0, stream>>>(ei, flag, deg);
    dinv_kernel<<<(N_NODES + 255) / 256, 256, 0, stream>>>(deg, dinv);
    int nb = (N_NODES + 255) / 256; // 196
    block_sum<<<nb, 256, 0, stream>>>(deg, bsum);
    scan_bsums<<<1, 256, 0, stream>>>(bsum, boff, nb);
    scan_block<<<nb, 256, 0, stream>>>(deg, boff, rowst);
    scatter_kernel<<<(N_EDGES + 255) / 256, 256, 0, stream>>>(ei, flag, rowst, dinv, fill, csr, cw);

    // pack 4 weight matrices into MFMA fragment layout (hi/lo bf16)
    dim3 pg(8, 4);
    pack_w<<<pg, 256, 0, stream>>>(W0, W1, W2, hW1, pkh, pkl);

    const float* bs[3]  = {b0, b1, b2};
    const float* gs[3]  = {g0, g1, g2};
    const float* bes[3] = {be0, be1, be2};
    const float* hin = x;
    int ngb = (N_NODES + 63) / 64; // 782
    for (int l = 0; l < 3; ++l) {
        agg_kernel<<<(N_NODES + 3) / 4, 256, 0, stream>>>(hin, dinv, rowst, csr, cw, hagg);
        gemm_mfma<<<ngb, 256, 0, stream>>>(hagg, pkh + (size_t)l * 16384, pkl + (size_t)l * 16384,
                                           bs[l], gs[l], bes[l], hbuf, 0, N_NODES);
        hin = hbuf;
    }
    // head layer 1: ReLU(h @ hW1 + hb1) -> hagg
    gemm_mfma<<<ngb, 256, 0, stream>>>(hbuf, pkh + (size_t)3 * 16384, pkl + (size_t)3 * 16384,
                                       hb1, nullptr, nullptr, hagg, 1, N_NODES);
    // head layer 2: dot with hW2
    head_dot<<<(N_NODES + 3) / 4, 256, 0, stream>>>(hagg, hW2, hb2, out);
}

// Round 3
// 290.495 us; speedup vs baseline: 1.5252x; 1.0478x over previous
//
#include <hip/hip_runtime.h>

#define N_NODES 50000
#define N_EDGES 600000
#define HDIM 128
#define EPS 1e-5f

typedef __attribute__((ext_vector_type(8))) short bf16x8;
typedef __attribute__((ext_vector_type(4))) float f32x4;

// ---------------- edge_index dtype detection (int32 vs int64) ----------------
__global__ void detect_kernel(const int* __restrict__ ei, int* __restrict__ flag) {
    __shared__ int nonzero;
    if (threadIdx.x == 0) nonzero = 0;
    __syncthreads();
    int acc = 0;
    for (int i = threadIdx.x; i < 1024; i += blockDim.x)
        acc |= ei[2 * i + 1];
    if (acc) atomicOr(&nonzero, 1);
    __syncthreads();
    if (threadIdx.x == 0) *flag = (nonzero == 0) ? 1 : 0;
}

__device__ __forceinline__ int load_idx(const int* __restrict__ ei, int pos, int f) {
    return f ? ei[2 * pos] : ei[pos];
}

// ---------------- degree / CSR build ----------------
__global__ void deg_kernel(const int* __restrict__ ei, const int* __restrict__ flag,
                           int* __restrict__ deg) {
    int e = blockIdx.x * blockDim.x + threadIdx.x;
    if (e >= N_EDGES) return;
    int f = *flag;
    int d = load_idx(ei, N_EDGES + e, f);
    atomicAdd(&deg[d], 1);
}

__global__ void dinv_kernel(const int* __restrict__ deg, float* __restrict__ dinv) {
    int i = blockIdx.x * blockDim.x + threadIdx.x;
    if (i < N_NODES) dinv[i] = rsqrtf((float)deg[i] + 1.0f); // +1 self-loop
}

__global__ void block_sum(const int* __restrict__ deg, int* __restrict__ bsum) {
    __shared__ int sm[256];
    int i = blockIdx.x * 256 + threadIdx.x;
    sm[threadIdx.x] = (i < N_NODES) ? deg[i] : 0;
    __syncthreads();
    for (int s = 128; s > 0; s >>= 1) {
        if (threadIdx.x < s) sm[threadIdx.x] += sm[threadIdx.x + s];
        __syncthreads();
    }
    if (threadIdx.x == 0) bsum[blockIdx.x] = sm[0];
}

__global__ void scan_bsums(const int* __restrict__ bsum, int* __restrict__ boff, int nb) {
    __shared__ int sm[256];
    int t = threadIdx.x;
    int v = (t < nb) ? bsum[t] : 0;
    sm[t] = v;
    __syncthreads();
    for (int s = 1; s < 256; s <<= 1) {
        int add = (t >= s) ? sm[t - s] : 0;
        __syncthreads();
        sm[t] += add;
        __syncthreads();
    }
    if (t < nb) boff[t] = sm[t] - v; // exclusive
}

__global__ void scan_block(const int* __restrict__ deg, const int* __restrict__ boff,
                           int* __restrict__ rowst) {
    __shared__ int sm[256];
    int t = threadIdx.x;
    int i = blockIdx.x * 256 + t;
    int v = (i < N_NODES) ? deg[i] : 0;
    sm[t] = v;
    __syncthreads();
    for (int s = 1; s < 256; s <<= 1) {
        int add = (t >= s) ? sm[t - s] : 0;
        __syncthreads();
        sm[t] += add;
        __syncthreads();
    }
    int excl = boff[blockIdx.x] + sm[t] - v;
    if (i < N_NODES) rowst[i] = excl;
    if (i == N_NODES - 1) rowst[N_NODES] = excl + v;
}

// scatter: also precompute per-edge weight cw = dinv[src]; pad csr/cw tails with 0
__global__ void scatter_kernel(const int* __restrict__ ei, const int* __restrict__ flag,
                               const int* __restrict__ rowst, const float* __restrict__ dinv,
                               int* __restrict__ fill, int* __restrict__ csr,
                               float* __restrict__ cw) {
    int e = blockIdx.x * blockDim.x + threadIdx.x;
    if (e >= N_EDGES) return;
    if (e < 16) { csr[N_EDGES + e] = 0; cw[N_EDGES + e] = 0.f; }
    int f = *flag;
    int s = load_idx(ei, e, f);
    int d = load_idx(ei, N_EDGES + e, f);
    int pos = rowst[d] + atomicAdd(&fill[d], 1);
    csr[pos] = s;
    cw[pos] = dinv[s];
}

// ---------------- aggregation: 2 nodes/wave (32 lanes x float4), 4-deep predicated MLP ----------------
__global__ __launch_bounds__(256) void agg_kernel(const float* __restrict__ h,
                                                  const float* __restrict__ dinv,
                                                  const int* __restrict__ rowst,
                                                  const int* __restrict__ csr,
                                                  const float* __restrict__ cw,
                                                  float* __restrict__ out) {
    int node = blockIdx.x * 8 + (threadIdx.x >> 5);
    int sub = threadIdx.x & 31;
    if (node >= N_NODES) return;
    const float4* h4 = (const float4*)h;
    float dd = dinv[node];
    float4 v = h4[(size_t)node * 32 + sub];
    float ax = dd * v.x, ay = dd * v.y, az = dd * v.z, aw = dd * v.w; // self (gets *dd below)
    int e1 = rowst[node + 1];
    for (int e = rowst[node]; e < e1; e += 4) {
        float w0 = cw[e];
        float w1 = (e + 1 < e1) ? cw[e + 1] : 0.f;
        float w2 = (e + 2 < e1) ? cw[e + 2] : 0.f;
        float w3 = (e + 3 < e1) ? cw[e + 3] : 0.f;
        int s0 = csr[e];
        int s1 = (e + 1 < e1) ? csr[e + 1] : s0;
        int s2 = (e + 2 < e1) ? csr[e + 2] : s0;
        int s3 = (e + 3 < e1) ? csr[e + 3] : s0;
        float4 u0 = h4[(size_t)s0 * 32 + sub];
        float4 u1 = h4[(size_t)s1 * 32 + sub];
        float4 u2 = h4[(size_t)s2 * 32 + sub];
        float4 u3 = h4[(size_t)s3 * 32 + sub];
        ax += w0 * u0.x; ay += w0 * u0.y; az += w0 * u0.z; aw += w0 * u0.w;
        ax += w1 * u1.x; ay += w1 * u1.y; az += w1 * u1.z; aw += w1 * u1.w;
        ax += w2 * u2.x; ay += w2 * u2.y; az += w2 * u2.z; aw += w2 * u2.w;
        ax += w3 * u3.x; ay += w3 * u3.y; az += w3 * u3.z; aw += w3 * u3.w;
    }
    float4 r;
    r.x = ax * dd; r.y = ay * dd; r.z = az * dd; r.w = aw * dd;
    ((float4*)out)[(size_t)node * 32 + sub] = r;
}

// ---------------- bf16 hi/lo split ----------------
__device__ __forceinline__ void bsplit(float a, short& hi, short& lo) {
    unsigned u = __float_as_uint(a);
    unsigned r = (u + 0x7FFFu + ((u >> 16) & 1u)) & 0xFFFF0000u; // RNE
    hi = (short)(r >> 16);
    float l = a - __uint_as_float(r);
    unsigned ul = __float_as_uint(l);
    unsigned rl = ul + 0x7FFFu + ((ul >> 16) & 1u);
    lo = (short)(rl >> 16);
}

// ---------------- pack W [128][128] fp32 -> per-lane MFMA B-fragments (hi/lo bf16) ----------------
// frag index = ((ks*8 + cf)*64 + lane)*8; lane holds B[ks*32 + (lane>>4)*8 + i][cf*16 + (lane&15)]
__global__ void pack_w(const float* __restrict__ W0, const float* __restrict__ W1,
                       const float* __restrict__ W2, const float* __restrict__ W3,
                       short* __restrict__ pkh, short* __restrict__ pkl) {
    const float* W = (blockIdx.y == 0) ? W0 : (blockIdx.y == 1) ? W1
                   : (blockIdx.y == 2) ? W2 : W3;
    int idx = blockIdx.x * 256 + threadIdx.x; // 0..2047
    int lane = idx & 63;
    int cf = (idx >> 6) & 7;
    int ks = idx >> 9;
    int col = cf * 16 + (lane & 15);
    int k0 = ks * 32 + (lane >> 4) * 8;
    short h[8], l[8];
#pragma unroll
    for (int i = 0; i < 8; ++i) bsplit(W[(size_t)(k0 + i) * HDIM + col], h[i], l[i]);
    size_t base = (size_t)blockIdx.y * 16384 + (size_t)idx * 8;
#pragma unroll
    for (int i = 0; i < 8; ++i) { pkh[base + i] = h[i]; pkl[base + i] = l[i]; }
}

// ---------------- MFMA GEMM, bf16x3 split ----------------
// 4 waves; wave = 16 rows x 128 cols; block = 64 rows.
// mode 0: LN*gamma+beta, ReLU -> out[row][col]
// mode 1: ReLU, then dot with w2 (gamma slot) + b2 (beta slot) -> logits out[row]
__global__ __launch_bounds__(256) void gemm_mfma(const float* __restrict__ A,
                                                 const short* __restrict__ Bh,
                                                 const short* __restrict__ Bl,
                                                 const float* __restrict__ bias,
                                                 const float* __restrict__ gamma,
                                                 const float* __restrict__ beta,
                                                 float* __restrict__ out,
                                                 int mode, int nrows) {
    int t = threadIdx.x;
    int wave = t >> 6, lane = t & 63;
    int lrow = lane & 15, lk = lane >> 4;
    int rowb = blockIdx.x * 64 + wave * 16;

    f32x4 acc[8];
#pragma unroll
    for (int cf = 0; cf < 8; ++cf) acc[cf] = (f32x4){0.f, 0.f, 0.f, 0.f};

    const float* arow = A + (size_t)(rowb + lrow) * HDIM;

#pragma unroll
    for (int ks = 0; ks < 4; ++ks) {
        const float* ap = arow + ks * 32 + lk * 8;
        float4 a0 = *(const float4*)ap;
        float4 a1 = *(const float4*)(ap + 4);
        float av[8] = {a0.x, a0.y, a0.z, a0.w, a1.x, a1.y, a1.z, a1.w};
        bf16x8 ah, al;
#pragma unroll
        for (int i = 0; i < 8; ++i) {
            short hh, ll;
            bsplit(av[i], hh, ll);
            ah[i] = hh; al[i] = ll;
        }
        const short* bhp = Bh + (size_t)(ks * 8) * 512 + (size_t)lane * 8;
        const short* blp = Bl + (size_t)(ks * 8) * 512 + (size_t)lane * 8;
#pragma unroll
        for (int cf = 0; cf < 8; ++cf) {
            bf16x8 bh = *(const bf16x8*)(bhp + (size_t)cf * 512);
            bf16x8 bl = *(const bf16x8*)(blp + (size_t)cf * 512);
            acc[cf] = __builtin_amdgcn_mfma_f32_16x16x32_bf16(ah, bh, acc[cf], 0, 0, 0);
            acc[cf] = __builtin_amdgcn_mfma_f32_16x16x32_bf16(ah, bl, acc[cf], 0, 0, 0);
            acc[cf] = __builtin_amdgcn_mfma_f32_16x16x32_bf16(al, bh, acc[cf], 0, 0, 0);
        }
    }

    // C/D layout: col = cf*16 + lrow, local row = lk*4 + r
    float bias_v[8];
#pragma unroll
    for (int cf = 0; cf < 8; ++cf) bias_v[cf] = bias[cf * 16 + lrow];

    if (mode == 0) {
        float gam[8], bet[8];
#pragma unroll
        for (int cf = 0; cf < 8; ++cf) {
            gam[cf] = gamma[cf * 16 + lrow];
            bet[cf] = beta[cf * 16 + lrow];
        }
#pragma unroll
        for (int r = 0; r < 4; ++r) {
            float vv[8];
            float s1 = 0.f, s2 = 0.f;
#pragma unroll
            for (int cf = 0; cf < 8; ++cf) {
                vv[cf] = acc[cf][r] + bias_v[cf];
                s1 += vv[cf];
                s2 += vv[cf] * vv[cf];
            }
#pragma unroll
            for (int m = 1; m <= 8; m <<= 1) {
                s1 += __shfl_xor(s1, m);
                s2 += __shfl_xor(s2, m);
            }
            float mean = s1 * (1.0f / 128.0f);
            float var = s2 * (1.0f / 128.0f) - mean * mean;
            float rs = rsqrtf(var + EPS);
            int row = rowb + lk * 4 + r;
            if (row < nrows) {
#pragma unroll
                for (int cf = 0; cf < 8; ++cf) {
                    float y = (vv[cf] - mean) * rs * gam[cf] + bet[cf];
                    out[(size_t)row * HDIM + cf * 16 + lrow] = y > 0.f ? y : 0.f;
                }
            }
        }
    } else {
        // fused head: logits[row] = sum_col relu(acc+bias) * w2[col] + b2
        float w2v[8];
#pragma unroll
        for (int cf = 0; cf < 8; ++cf) w2v[cf] = gamma[cf * 16 + lrow];
        float b2 = beta[0];
#pragma unroll
        for (int r = 0; r < 4; ++r) {
            float part = 0.f;
#pragma unroll
            for (int cf = 0; cf < 8; ++cf) {
                float y = acc[cf][r] + bias_v[cf];
                y = y > 0.f ? y : 0.f;
                part += y * w2v[cf];
            }
#pragma unroll
            for (int m = 1; m <= 8; m <<= 1) part += __shfl_xor(part, m);
            int row = rowb + lk * 4 + r;
            if (row < nrows && lrow == 0) out[row] = part + b2;
        }
    }
}

extern "C" void kernel_launch(void* const* d_in, const int* in_sizes, int n_in,
                              void* d_out, int out_size, void* d_ws, size_t ws_size,
                              hipStream_t stream) {
    (void)in_sizes; (void)n_in; (void)out_size; (void)ws_size;
    const float* x   = (const float*)d_in[0];
    const int*   ei  = (const int*)d_in[1];
    const float* W0  = (const float*)d_in[2];
    const float* b0  = (const float*)d_in[3];
    const float* g0  = (const float*)d_in[4];
    const float* be0 = (const float*)d_in[5];
    const float* W1  = (const float*)d_in[6];
    const float* b1  = (const float*)d_in[7];
    const float* g1  = (const float*)d_in[8];
    const float* be1 = (const float*)d_in[9];
    const float* W2  = (const float*)d_in[10];
    const float* b2  = (const float*)d_in[11];
    const float* g2  = (const float*)d_in[12];
    const float* be2 = (const float*)d_in[13];
    const float* hW1 = (const float*)d_in[14];
    const float* hb1 = (const float*)d_in[15];
    const float* hW2 = (const float*)d_in[16];
    const float* hb2 = (const float*)d_in[17];
    float* out = (float*)d_out;

    char* w = (char*)d_ws;
    size_t off = 0;
    auto alloc = [&](size_t bytes) -> void* {
        void* p = w + off;
        off += (bytes + 255) & ~(size_t)255;
        return p;
    };
    float* dinv  = (float*)alloc((size_t)N_NODES * 4);
    int*   deg   = (int*)alloc((size_t)N_NODES * 4);
    int*   fill  = (int*)alloc((size_t)N_NODES * 4);
    int*   rowst = (int*)alloc((size_t)(N_NODES + 1) * 4);
    int*   csr   = (int*)alloc((size_t)(N_EDGES + 16) * 4);
    float* cw    = (float*)alloc((size_t)(N_EDGES + 16) * 4);
    int*   bsum  = (int*)alloc(256 * 4);
    int*   boff  = (int*)alloc(256 * 4);
    int*   flag  = (int*)alloc(256);
    float* hagg  = (float*)alloc((size_t)N_NODES * HDIM * 4);
    float* hbuf  = (float*)alloc((size_t)N_NODES * HDIM * 4);
    short* pkh   = (short*)alloc((size_t)4 * 16384 * 2);
    short* pkl   = (short*)alloc((size_t)4 * 16384 * 2);

    hipMemsetAsync(deg, 0, (size_t)N_NODES * 4, stream);
    hipMemsetAsync(fill, 0, (size_t)N_NODES * 4, stream);

    detect_kernel<<<1, 256, 0, stream>>>(ei, flag);
    deg_kernel<<<(N_EDGES + 255) / 256, 256, 0, stream>>>(ei, flag, deg);
    dinv_kernel<<<(N_NODES + 255) / 256, 256, 0, stream>>>(deg, dinv);
    int nb = (N_NODES + 255) / 256; // 196
    block_sum<<<nb, 256, 0, stream>>>(deg, bsum);
    scan_bsums<<<1, 256, 0, stream>>>(bsum, boff, nb);
    scan_block<<<nb, 256, 0, stream>>>(deg, boff, rowst);
    scatter_kernel<<<(N_EDGES + 255) / 256, 256, 0, stream>>>(ei, flag, rowst, dinv, fill, csr, cw);

    dim3 pg(8, 4);
    pack_w<<<pg, 256, 0, stream>>>(W0, W1, W2, hW1, pkh, pkl);

    const float* bs[3]  = {b0, b1, b2};
    const float* gs[3]  = {g0, g1, g2};
    const float* bes[3] = {be0, be1, be2};
    const float* hin = x;
    int ngb = (N_NODES + 63) / 64; // 782
    for (int l = 0; l < 3; ++l) {
        agg_kernel<<<(N_NODES + 7) / 8, 256, 0, stream>>>(hin, dinv, rowst, csr, cw, hagg);
        gemm_mfma<<<ngb, 256, 0, stream>>>(hagg, pkh + (size_t)l * 16384, pkl + (size_t)l * 16384,
                                           bs[l], gs[l], bes[l], hbuf, 0, N_NODES);
        hin = hbuf;
    }
    // fused head: ReLU(h @ hW1 + hb1) @ hW2 + hb2 -> logits
    gemm_mfma<<<ngb, 256, 0, stream>>>(hbuf, pkh + (size_t)3 * 16384, pkl + (size_t)3 * 16384,
                                       hb1, hW2, hb2, out, 1, N_NODES);
}

// Round 4
// 271.965 us; speedup vs baseline: 1.6291x; 1.0681x over previous
//
#include <hip/hip_runtime.h>

#define N_NODES 50000
#define N_EDGES 600000
#define HDIM 128
#define EPS 1e-5f
#define LPAD 132

typedef __attribute__((ext_vector_type(8))) short bf16x8;
typedef __attribute__((ext_vector_type(4))) float f32x4;

// ---------------- edge_index dtype detection (int32 vs int64) ----------------
__global__ void detect_kernel(const int* __restrict__ ei, int* __restrict__ flag) {
    __shared__ int nonzero;
    if (threadIdx.x == 0) nonzero = 0;
    __syncthreads();
    int acc = 0;
    for (int i = threadIdx.x; i < 1024; i += blockDim.x)
        acc |= ei[2 * i + 1];
    if (acc) atomicOr(&nonzero, 1);
    __syncthreads();
    if (threadIdx.x == 0) *flag = (nonzero == 0) ? 1 : 0;
}

__device__ __forceinline__ int load_idx(const int* __restrict__ ei, int pos, int f) {
    return f ? ei[2 * pos] : ei[pos];
}

// ---------------- degree / CSR build ----------------
__global__ void deg_kernel(const int* __restrict__ ei, const int* __restrict__ flag,
                           int* __restrict__ deg) {
    int e = blockIdx.x * blockDim.x + threadIdx.x;
    if (e >= N_EDGES) return;
    int f = *flag;
    int d = load_idx(ei, N_EDGES + e, f);
    atomicAdd(&deg[d], 1);
}

__global__ void dinv_kernel(const int* __restrict__ deg, float* __restrict__ dinv) {
    int i = blockIdx.x * blockDim.x + threadIdx.x;
    if (i < N_NODES) dinv[i] = rsqrtf((float)deg[i] + 1.0f); // +1 self-loop
}

__global__ void block_sum(const int* __restrict__ deg, int* __restrict__ bsum) {
    __shared__ int sm[256];
    int i = blockIdx.x * 256 + threadIdx.x;
    sm[threadIdx.x] = (i < N_NODES) ? deg[i] : 0;
    __syncthreads();
    for (int s = 128; s > 0; s >>= 1) {
        if (threadIdx.x < s) sm[threadIdx.x] += sm[threadIdx.x + s];
        __syncthreads();
    }
    if (threadIdx.x == 0) bsum[blockIdx.x] = sm[0];
}

__global__ void scan_bsums(const int* __restrict__ bsum, int* __restrict__ boff, int nb) {
    __shared__ int sm[256];
    int t = threadIdx.x;
    int v = (t < nb) ? bsum[t] : 0;
    sm[t] = v;
    __syncthreads();
    for (int s = 1; s < 256; s <<= 1) {
        int add = (t >= s) ? sm[t - s] : 0;
        __syncthreads();
        sm[t] += add;
        __syncthreads();
    }
    if (t < nb) boff[t] = sm[t] - v; // exclusive
}

__global__ void scan_block(const int* __restrict__ deg, const int* __restrict__ boff,
                           int* __restrict__ rowst) {
    __shared__ int sm[256];
    int t = threadIdx.x;
    int i = blockIdx.x * 256 + t;
    int v = (i < N_NODES) ? deg[i] : 0;
    sm[t] = v;
    __syncthreads();
    for (int s = 1; s < 256; s <<= 1) {
        int add = (t >= s) ? sm[t - s] : 0;
        __syncthreads();
        sm[t] += add;
        __syncthreads();
    }
    int excl = boff[blockIdx.x] + sm[t] - v;
    if (i < N_NODES) rowst[i] = excl;
    if (i == N_NODES - 1) rowst[N_NODES] = excl + v;
}

// scatter: single packed 8B store per edge {src, bits(dinv[src])}; pad tail 16
__global__ void scatter_kernel(const int* __restrict__ ei, const int* __restrict__ flag,
                               const int* __restrict__ rowst, const float* __restrict__ dinv,
                               int* __restrict__ fill, int2* __restrict__ ecsr) {
    int e = blockIdx.x * blockDim.x + threadIdx.x;
    if (e >= N_EDGES) return;
    if (e < 16) ecsr[N_EDGES + e] = make_int2(0, 0);
    int f = *flag;
    int s = load_idx(ei, e, f);
    int d = load_idx(ei, N_EDGES + e, f);
    int pos = rowst[d] + atomicAdd(&fill[d], 1);
    ecsr[pos] = make_int2(s, __float_as_int(dinv[s]));
}

// ---------------- bf16 hi/lo split ----------------
__device__ __forceinline__ void bsplit(float a, short& hi, short& lo) {
    unsigned u = __float_as_uint(a);
    unsigned r = (u + 0x7FFFu + ((u >> 16) & 1u)) & 0xFFFF0000u; // RNE
    hi = (short)(r >> 16);
    float l = a - __uint_as_float(r);
    unsigned ul = __float_as_uint(l);
    unsigned rl = ul + 0x7FFFu + ((ul >> 16) & 1u);
    lo = (short)(rl >> 16);
}

// ---------------- pack W [128][128] fp32 -> per-lane MFMA B-fragments (hi/lo bf16) ----------------
// frag index = ((ks*8 + cf)*64 + lane)*8; lane holds B[ks*32 + (lane>>4)*8 + i][cf*16 + (lane&15)]
__global__ void pack_w(const float* __restrict__ W0, const float* __restrict__ W1,
                       const float* __restrict__ W2, const float* __restrict__ W3,
                       short* __restrict__ pkh, short* __restrict__ pkl) {
    const float* W = (blockIdx.y == 0) ? W0 : (blockIdx.y == 1) ? W1
                   : (blockIdx.y == 2) ? W2 : W3;
    int idx = blockIdx.x * 256 + threadIdx.x; // 0..2047
    int lane = idx & 63;
    int cf = (idx >> 6) & 7;
    int ks = idx >> 9;
    int col = cf * 16 + (lane & 15);
    int k0 = ks * 32 + (lane >> 4) * 8;
    short h[8], l[8];
#pragma unroll
    for (int i = 0; i < 8; ++i) bsplit(W[(size_t)(k0 + i) * HDIM + col], h[i], l[i]);
    size_t base = (size_t)blockIdx.y * 16384 + (size_t)idx * 8;
#pragma unroll
    for (int i = 0; i < 8; ++i) { pkh[base + i] = h[i]; pkl[base + i] = l[i]; }
}

// ---------------- fused layer: aggregate 64 rows into LDS, then MFMA GEMM + bias + LN + ReLU ----------------
__global__ __launch_bounds__(256) void layer_fused(const float* __restrict__ h,
                                                   const float* __restrict__ dinv,
                                                   const int* __restrict__ rowst,
                                                   const int2* __restrict__ ecsr,
                                                   const short* __restrict__ Bh,
                                                   const short* __restrict__ Bl,
                                                   const float* __restrict__ bias,
                                                   const float* __restrict__ gamma,
                                                   const float* __restrict__ beta,
                                                   float* __restrict__ out, int nrows) {
    __shared__ float As[64][LPAD]; // 33 KB
    int t = threadIdx.x;
    int blockRow = blockIdx.x * 64;

    // ---- phase 1: aggregate (half-wave = 32 lanes per row, 8 rows each) ----
    {
        int half = t >> 5, sub = t & 31;
        const float4* h4 = (const float4*)h;
        for (int r8 = 0; r8 < 8; ++r8) {
            int rl = half * 8 + r8;
            int node = blockRow + rl;
            float4 res = make_float4(0.f, 0.f, 0.f, 0.f);
            if (node < nrows) {
                float dd = dinv[node];
                float4 v = h4[(size_t)node * 32 + sub];
                float ax = dd * v.x, ay = dd * v.y, az = dd * v.z, aw = dd * v.w;
                int e1 = rowst[node + 1];
                for (int e = rowst[node]; e < e1; e += 4) {
                    int2 p0 = ecsr[e];
                    int2 p1 = ecsr[e + 1];
                    int2 p2 = ecsr[e + 2];
                    int2 p3 = ecsr[e + 3];
                    int s0 = p0.x;
                    float w0 = __int_as_float(p0.y);
                    int s1 = (e + 1 < e1) ? p1.x : s0;
                    float w1 = (e + 1 < e1) ? __int_as_float(p1.y) : 0.f;
                    int s2 = (e + 2 < e1) ? p2.x : s0;
                    float w2 = (e + 2 < e1) ? __int_as_float(p2.y) : 0.f;
                    int s3 = (e + 3 < e1) ? p3.x : s0;
                    float w3 = (e + 3 < e1) ? __int_as_float(p3.y) : 0.f;
                    float4 u0 = h4[(size_t)s0 * 32 + sub];
                    float4 u1 = h4[(size_t)s1 * 32 + sub];
                    float4 u2 = h4[(size_t)s2 * 32 + sub];
                    float4 u3 = h4[(size_t)s3 * 32 + sub];
                    ax += w0 * u0.x; ay += w0 * u0.y; az += w0 * u0.z; aw += w0 * u0.w;
                    ax += w1 * u1.x; ay += w1 * u1.y; az += w1 * u1.z; aw += w1 * u1.w;
                    ax += w2 * u2.x; ay += w2 * u2.y; az += w2 * u2.z; aw += w2 * u2.w;
                    ax += w3 * u3.x; ay += w3 * u3.y; az += w3 * u3.z; aw += w3 * u3.w;
                }
                res = make_float4(ax * dd, ay * dd, az * dd, aw * dd);
            }
            *(float4*)&As[rl][sub * 4] = res;
        }
    }
    __syncthreads();

    // ---- phase 2: MFMA GEMM (bf16x4 split) + epilogue ----
    int wave = t >> 6, lane = t & 63;
    int lrow = lane & 15, lk = lane >> 4;
    int rowb = blockRow + wave * 16;

    f32x4 acc[8];
#pragma unroll
    for (int cf = 0; cf < 8; ++cf) acc[cf] = (f32x4){0.f, 0.f, 0.f, 0.f};

#pragma unroll
    for (int ks = 0; ks < 4; ++ks) {
        const float* ap = &As[wave * 16 + lrow][ks * 32 + lk * 8];
        float4 a0 = *(const float4*)ap;
        float4 a1 = *(const float4*)(ap + 4);
        float av[8] = {a0.x, a0.y, a0.z, a0.w, a1.x, a1.y, a1.z, a1.w};
        bf16x8 ah, al;
#pragma unroll
        for (int i = 0; i < 8; ++i) {
            short hh, ll;
            bsplit(av[i], hh, ll);
            ah[i] = hh; al[i] = ll;
        }
        const short* bhp = Bh + (size_t)(ks * 8) * 512 + (size_t)lane * 8;
        const short* blp = Bl + (size_t)(ks * 8) * 512 + (size_t)lane * 8;
#pragma unroll
        for (int cf = 0; cf < 8; ++cf) {
            bf16x8 bh = *(const bf16x8*)(bhp + (size_t)cf * 512);
            bf16x8 bl = *(const bf16x8*)(blp + (size_t)cf * 512);
            acc[cf] = __builtin_amdgcn_mfma_f32_16x16x32_bf16(ah, bh, acc[cf], 0, 0, 0);
            acc[cf] = __builtin_amdgcn_mfma_f32_16x16x32_bf16(ah, bl, acc[cf], 0, 0, 0);
            acc[cf] = __builtin_amdgcn_mfma_f32_16x16x32_bf16(al, bh, acc[cf], 0, 0, 0);
            acc[cf] = __builtin_amdgcn_mfma_f32_16x16x32_bf16(al, bl, acc[cf], 0, 0, 0);
        }
    }

    // C/D layout: col = cf*16 + lrow, local row = lk*4 + r
    float bias_v[8], gam[8], bet[8];
#pragma unroll
    for (int cf = 0; cf < 8; ++cf) {
        bias_v[cf] = bias[cf * 16 + lrow];
        gam[cf] = gamma[cf * 16 + lrow];
        bet[cf] = beta[cf * 16 + lrow];
    }
#pragma unroll
    for (int r = 0; r < 4; ++r) {
        float vv[8];
        float s1 = 0.f;
#pragma unroll
        for (int cf = 0; cf < 8; ++cf) {
            vv[cf] = acc[cf][r] + bias_v[cf];
            s1 += vv[cf];
        }
#pragma unroll
        for (int m = 1; m <= 8; m <<= 1) s1 += __shfl_xor(s1, m);
        float mean = s1 * (1.0f / 128.0f);
        float s2 = 0.f;
        float cc[8];
#pragma unroll
        for (int cf = 0; cf < 8; ++cf) {
            cc[cf] = vv[cf] - mean;
            s2 += cc[cf] * cc[cf];
        }
#pragma unroll
        for (int m = 1; m <= 8; m <<= 1) s2 += __shfl_xor(s2, m);
        float var = s2 * (1.0f / 128.0f);
        float rs = rsqrtf(var + EPS);
        int row = rowb + lk * 4 + r;
        if (row < nrows) {
#pragma unroll
            for (int cf = 0; cf < 8; ++cf) {
                float y = cc[cf] * rs * gam[cf] + bet[cf];
                out[(size_t)row * HDIM + cf * 16 + lrow] = y > 0.f ? y : 0.f;
            }
        }
    }
}

// ---------------- head: logits = ReLU(A@hW1+hb1)@hW2 + hb2, fused ----------------
__global__ __launch_bounds__(256) void head_mfma(const float* __restrict__ A,
                                                 const short* __restrict__ Bh,
                                                 const short* __restrict__ Bl,
                                                 const float* __restrict__ bias,
                                                 const float* __restrict__ w2,
                                                 const float* __restrict__ b2p,
                                                 float* __restrict__ out, int nrows) {
    int t = threadIdx.x;
    int wave = t >> 6, lane = t & 63;
    int lrow = lane & 15, lk = lane >> 4;
    int rowb = blockIdx.x * 64 + wave * 16;

    f32x4 acc[8];
#pragma unroll
    for (int cf = 0; cf < 8; ++cf) acc[cf] = (f32x4){0.f, 0.f, 0.f, 0.f};

    const float* arow = A + (size_t)(rowb + lrow) * HDIM;
#pragma unroll
    for (int ks = 0; ks < 4; ++ks) {
        const float* ap = arow + ks * 32 + lk * 8;
        float4 a0 = *(const float4*)ap;
        float4 a1 = *(const float4*)(ap + 4);
        float av[8] = {a0.x, a0.y, a0.z, a0.w, a1.x, a1.y, a1.z, a1.w};
        bf16x8 ah, al;
#pragma unroll
        for (int i = 0; i < 8; ++i) {
            short hh, ll;
            bsplit(av[i], hh, ll);
            ah[i] = hh; al[i] = ll;
        }
        const short* bhp = Bh + (size_t)(ks * 8) * 512 + (size_t)lane * 8;
        const short* blp = Bl + (size_t)(ks * 8) * 512 + (size_t)lane * 8;
#pragma unroll
        for (int cf = 0; cf < 8; ++cf) {
            bf16x8 bh = *(const bf16x8*)(bhp + (size_t)cf * 512);
            bf16x8 bl = *(const bf16x8*)(blp + (size_t)cf * 512);
            acc[cf] = __builtin_amdgcn_mfma_f32_16x16x32_bf16(ah, bh, acc[cf], 0, 0, 0);
            acc[cf] = __builtin_amdgcn_mfma_f32_16x16x32_bf16(ah, bl, acc[cf], 0, 0, 0);
            acc[cf] = __builtin_amdgcn_mfma_f32_16x16x32_bf16(al, bh, acc[cf], 0, 0, 0);
            acc[cf] = __builtin_amdgcn_mfma_f32_16x16x32_bf16(al, bl, acc[cf], 0, 0, 0);
        }
    }

    float bias_v[8], w2v[8];
#pragma unroll
    for (int cf = 0; cf < 8; ++cf) {
        bias_v[cf] = bias[cf * 16 + lrow];
        w2v[cf] = w2[cf * 16 + lrow];
    }
    float b2 = b2p[0];
#pragma unroll
    for (int r = 0; r < 4; ++r) {
        float part = 0.f;
#pragma unroll
        for (int cf = 0; cf < 8; ++cf) {
            float y = acc[cf][r] + bias_v[cf];
            y = y > 0.f ? y : 0.f;
            part += y * w2v[cf];
        }
#pragma unroll
        for (int m = 1; m <= 8; m <<= 1) part += __shfl_xor(part, m);
        int row = rowb + lk * 4 + r;
        if (row < nrows && lrow == 0) out[row] = part + b2;
    }
}

extern "C" void kernel_launch(void* const* d_in, const int* in_sizes, int n_in,
                              void* d_out, int out_size, void* d_ws, size_t ws_size,
                              hipStream_t stream) {
    (void)in_sizes; (void)n_in; (void)out_size; (void)ws_size;
    const float* x   = (const float*)d_in[0];
    const int*   ei  = (const int*)d_in[1];
    const float* W0  = (const float*)d_in[2];
    const float* b0  = (const float*)d_in[3];
    const float* g0  = (const float*)d_in[4];
    const float* be0 = (const float*)d_in[5];
    const float* W1  = (const float*)d_in[6];
    const float* b1  = (const float*)d_in[7];
    const float* g1  = (const float*)d_in[8];
    const float* be1 = (const float*)d_in[9];
    const float* W2  = (const float*)d_in[10];
    const float* b2  = (const float*)d_in[11];
    const float* g2  = (const float*)d_in[12];
    const float* be2 = (const float*)d_in[13];
    const float* hW1 = (const float*)d_in[14];
    const float* hb1 = (const float*)d_in[15];
    const float* hW2 = (const float*)d_in[16];
    const float* hb2 = (const float*)d_in[17];
    float* out = (float*)d_out;

    char* w = (char*)d_ws;
    size_t off = 0;
    auto alloc = [&](size_t bytes) -> void* {
        void* p = w + off;
        off += (bytes + 255) & ~(size_t)255;
        return p;
    };
    float* dinv  = (float*)alloc((size_t)N_NODES * 4);
    int*   deg   = (int*)alloc((size_t)N_NODES * 4);
    int*   fill  = (int*)alloc((size_t)N_NODES * 4);
    int*   rowst = (int*)alloc((size_t)(N_NODES + 1) * 4);
    int2*  ecsr  = (int2*)alloc((size_t)(N_EDGES + 16) * 8);
    int*   bsum  = (int*)alloc(256 * 4);
    int*   boff  = (int*)alloc(256 * 4);
    int*   flag  = (int*)alloc(256);
    float* hbufA = (float*)alloc((size_t)N_NODES * HDIM * 4);
    float* hbufB = (float*)alloc((size_t)N_NODES * HDIM * 4);
    short* pkh   = (short*)alloc((size_t)4 * 16384 * 2);
    short* pkl   = (short*)alloc((size_t)4 * 16384 * 2);

    hipMemsetAsync(deg, 0, (size_t)N_NODES * 4, stream);
    hipMemsetAsync(fill, 0, (size_t)N_NODES * 4, stream);

    detect_kernel<<<1, 256, 0, stream>>>(ei, flag);
    deg_kernel<<<(N_EDGES + 255) / 256, 256, 0, stream>>>(ei, flag, deg);
    dinv_kernel<<<(N_NODES + 255) / 256, 256, 0, stream>>>(deg, dinv);
    int nb = (N_NODES + 255) / 256; // 196
    block_sum<<<nb, 256, 0, stream>>>(deg, bsum);
    scan_bsums<<<1, 256, 0, stream>>>(bsum, boff, nb);
    scan_block<<<nb, 256, 0, stream>>>(deg, boff, rowst);
    scatter_kernel<<<(N_EDGES + 255) / 256, 256, 0, stream>>>(ei, flag, rowst, dinv, fill, ecsr);

    dim3 pg(8, 4);
    pack_w<<<pg, 256, 0, stream>>>(W0, W1, W2, hW1, pkh, pkl);

    int ngb = (N_NODES + 63) / 64; // 782
    // layer 0: x -> hbufA
    layer_fused<<<ngb, 256, 0, stream>>>(x, dinv, rowst, ecsr, pkh, pkl,
                                         b0, g0, be0, hbufA, N_NODES);
    // layer 1: hbufA -> hbufB
    layer_fused<<<ngb, 256, 0, stream>>>(hbufA, dinv, rowst, ecsr,
                                         pkh + (size_t)16384, pkl + (size_t)16384,
                                         b1, g1, be1, hbufB, N_NODES);
    // layer 2: hbufB -> hbufA
    layer_fused<<<ngb, 256, 0, stream>>>(hbufB, dinv, rowst, ecsr,
                                         pkh + (size_t)2 * 16384, pkl + (size_t)2 * 16384,
                                         b2, g2, be2, hbufA, N_NODES);
    // head: ReLU(hbufA @ hW1 + hb1) @ hW2 + hb2 -> out
    head_mfma<<<ngb, 256, 0, stream>>>(hbufA, pkh + (size_t)3 * 16384, pkl + (size_t)3 * 16384,
                                       hb1, hW2, hb2, out, N_NODES);
}